// Round 11
// baseline (78.254 us; speedup 1.0000x reference)
//
#include <hip/hip_runtime.h>
#include <hip/hip_bf16.h>

// AWQ 4-bit linear: out[32,11008] = x[32,4096] @ ((q - z)*s) + bias
// ROUND 11 = COUNTER-VISIBILITY ROUND. Kernels are functionally identical
// to round 10 (35.7 us), but each repeats its body internally (main x4,
// reduce x4, xconv x16; idempotent, memory-clobber per rep to defeat LICM)
// so each dispatch out-ranks the harness's 44-us ws-poison fills and
// finally appears in the rocprof top-5 with full counters.
// Per-kernel time = dur_us / REP.

#define IN_F   4096
#define OUT_F  11008
#define WCOLS  1376
#define NCOLB  86                 // 11008/128
#define KSPLIT 16
#define CHUNK  (IN_F/KSPLIT)      // 256
#define NTILE  (CHUNK/32)         // 8
#define NBLK   (NCOLB*KSPLIT)     // 1376
#define MROWS  32
#define SLAB   (MROWS*OUT_F)      // floats per k-partial slab (352256)
#define REP_MAIN 4
#define REP_RED  4
#define REP_XC   16

typedef __attribute__((ext_vector_type(2))) _Float16 half2v;
typedef __attribute__((ext_vector_type(4))) _Float16 half4v;
typedef __attribute__((ext_vector_type(8))) _Float16 half8v;
typedef __attribute__((ext_vector_type(4))) float    f32x4;
typedef __attribute__((ext_vector_type(4))) int      int4v;

__device__ __forceinline__ f32x4 mfma16h(half8v a, half8v b, f32x4 c) {
  return __builtin_amdgcn_mfma_f32_16x16x32_f16(a, b, c, 0, 0, 0);
}
__device__ __forceinline__ half2v splat_h(float f) {
  unsigned short b = __builtin_bit_cast(unsigned short, (_Float16)f);
  unsigned int u = (unsigned int)b | ((unsigned int)b << 16);
  return __builtin_bit_cast(half2v, u);
}

__global__ void awq_init(const float* __restrict__ bias, float* __restrict__ out) {
  int o = blockIdx.x * 256 + threadIdx.x;
  out[blockIdx.y * OUT_F + o] = bias[o];
}

__global__ void xconv(const float* __restrict__ x, _Float16* __restrict__ xb) {
  int i = blockIdx.x * 256 + threadIdx.x;          // 128 blocks -> 32768 f32x4
  for (int rep = 0; rep < REP_XC; ++rep) {
    asm volatile("" ::: "memory");
    f32x4 v = ((const f32x4*)x)[i];
    half4v o;
    #pragma unroll
    for (int j = 0; j < 4; ++j) o[j] = (_Float16)v[j];
    ((half4v*)xb)[i] = o;
  }
}

__global__ __launch_bounds__(256) void awq_reduce(
    const float* __restrict__ ws, const float* __restrict__ bias,
    float* __restrict__ out)
{
  const int i = blockIdx.x * 256 + threadIdx.x;    // f32x4 id, 88064 total
  for (int rep = 0; rep < REP_RED; ++rep) {
    asm volatile("" ::: "memory");
    const f32x4* w4 = (const f32x4*)ws;
    f32x4 s = w4[i];
    #pragma unroll
    for (int k = 1; k < KSPLIT; ++k) s += w4[k * (SLAB / 4) + i];
    const f32x4 b = *(const f32x4*)(bias + (i % (OUT_F / 4)) * 4);
    ((f32x4*)out)[i] = s + b;
  }
}

template<bool PRE, bool TOWS>
__global__ __launch_bounds__(256, 4) void awq_main(
    const float* __restrict__ x, const _Float16* __restrict__ xb,
    const int* __restrict__ qw, const int* __restrict__ qz,
    const float* __restrict__ sc, float* __restrict__ outp)
{
  // Per-wave private staging, swizzled: [buf][wave][512 dwords] = 16 KB.
  __shared__ int lds[2][4][512];

  const int tid  = threadIdx.x;
  const int w    = tid >> 6;           // wave -> 32-col subtile
  const int lane = tid & 63;
  const int q4   = lane >> 4;          // MFMA k-octet
  const int cl   = lane & 15;          // MFMA col-in-frag
  const int ww   = lane & 3;           // dequant: word 0..3 -> cols 8ww..8ww+7
  const int kp2  = lane >> 2;          // dequant: k-pair 0..15
  const int qx   = kp2 >> 2;           // quad of kp
  const int kq   = kp2 & 3;            // kp within quad

  // Bijective XCD swizzle (1376 = 8*172)
  const int b  = blockIdx.x;
  const int L  = (b & 7) * (NBLK / 8) + (b >> 3);
  const int colblk = L % NCOLB;
  const int kchunk = L / NCOLB;

  const int cb  = colblk * 128;        // first output column
  const int wcb = colblk * 16;         // first packed word
  const int K0  = kchunk * CHUNK;
  const int g0  = kchunk * (CHUNK / 128);   // 2 groups per chunk
  const int wq  = wcb + 4 * w + ww;    // lane's packed-word column

  // group constants: raw staging -> fp16 splat pairs
  f32x4 sra, srb; int zrw;
  half2v nz[8], ss[8];
  auto load_group_raw = [&](int g) {
    sra = *(const f32x4*)(sc + g * OUT_F + cb + w * 32 + ww * 8);
    srb = *(const f32x4*)(sc + g * OUT_F + cb + w * 32 + ww * 8 + 4);
    zrw = qz[g * WCOLS + wq];
  };
  auto conv_group = [&]() {
    #pragma unroll
    for (int l = 0; l < 8; ++l) {
      const int sh = 4 * (l >> 1) + 16 * (l & 1);   // 4*REV[l]
      const int zi = (zrw >> sh) & 15;
      nz[l] = splat_h(-(float)(1024 + zi));
      ss[l] = splat_h((l < 4) ? sra[l] : srb[l - 4]);
    }
  };
  auto load_q = [&](int t, int& q0, int& q1) {
    const int r = (K0 + t * 32 + 2 * kp2) * WCOLS + wq;
    q0 = qw[r];
    q1 = qw[r + WCOLS];
  };
  auto load_a = [&](int t, int mf) -> half8v {
    const int m = cl + 16 * mf;
    const int k = K0 + t * 32 + q4 * 8;
    if constexpr (PRE) {
      return *(const half8v*)(xb + m * IN_F + k);
    } else {
      const f32x4* xp = (const f32x4*)(x + m * IN_F + k);
      f32x4 lo = xp[0], hi = xp[1];
      half8v af;
      #pragma unroll
      for (int j = 0; j < 4; ++j) { af[j] = (_Float16)lo[j]; af[4+j] = (_Float16)hi[j]; }
      return af;
    }
  };
  // read B frag (cols cl / cl+16, k = 8q4..8q4+7), swizzle-inverse of store
  auto read_b = [&](int p, int frag) -> half8v {
    const int s0 = ((cl & 7) << 2) | (cl >> 3);
    const int qp = (q4 ^ ((cl >> 1) & 3)) << 2;
    const int idx = (s0 + 2 * frag) * 16 + qp;
    return __builtin_bit_cast(half8v, *(const int4v*)&lds[p][w][idx]);
  };

  for (int rep = 0; rep < REP_MAIN; ++rep) {
    asm volatile("" ::: "memory");     // defeat cross-rep load reuse/LICM

    // ---- prologue
    load_group_raw(g0);
    conv_group();
    int q0a, q1a, q0b, q1b, q0c, q1c;
    load_q(0, q0a, q1a);
    load_q(1, q0b, q1b);
    load_q(2, q0c, q1c);
    f32x4 acc[2][2] = {};

    #pragma unroll 4
    for (int t = 0; t < NTILE; ++t) {
      half8v a0 = load_a(t, 0), a1 = load_a(t, 1);
      int q0n = 0, q1n = 0;
      if (t + 3 < NTILE) load_q(t + 3, q0n, q1n);          // ring refill
      if (t == 2) load_group_raw(g0 + 1);                  // raw 2 tiles early
      if (t == 4) conv_group();                            // group 1 live t>=4

      // fp16 perm-dequant
      const int p  = t & 1;
      const int h0 = (unsigned)q0a >> 4;
      const int h1 = (unsigned)q1a >> 4;
      #pragma unroll
      for (int l = 0; l < 8; ++l) {
        const int pb = 2 * (l & 1) + (l >> 2);             // source byte
        const unsigned sel = (unsigned)(4 + pb) | ((unsigned)(4 + pb) << 8)
                           | ((unsigned)pb << 16) | ((unsigned)pb << 24);
        const int x0 = ((l >> 1) & 1) ? h0 : q0a;
        const int x1 = ((l >> 1) & 1) ? h1 : q1a;
        unsigned P = __builtin_amdgcn_perm((unsigned)x0, (unsigned)x1, sel);
        unsigned W = (P & 0x000F000Fu) | 0x64006400u;      // h2: 1024+n
        half2v wh = (__builtin_bit_cast(half2v, W) + nz[l]) * ss[l];
        const int idx = (l * 4 + ww) * 16 + ((qx ^ ((l >> 1) & 3)) << 2) + kq;
        lds[p][w][idx] = __builtin_bit_cast(int, wh);
      }
      // no barrier: same-wave ds_write -> ds_read via lgkmcnt only

      half8v bf0 = read_b(p, 0);
      half8v bf1 = read_b(p, 1);

      acc[0][0] = mfma16h(a0, bf0, acc[0][0]);
      acc[0][1] = mfma16h(a0, bf1, acc[0][1]);
      acc[1][0] = mfma16h(a1, bf0, acc[1][0]);
      acc[1][1] = mfma16h(a1, bf1, acc[1][1]);

      q0a = q0b; q1a = q1b;
      q0b = q0c; q1b = q1c;
      q0c = q0n; q1c = q1n;
    }

    // ---- epilogue (same values every rep -> idempotent)
    const int col0 = cb + w * 32 + cl;
    const int r0 = q4 * 4;
    if constexpr (TOWS) {
      float* wsp = outp + kchunk * SLAB;
      #pragma unroll
      for (int mf = 0; mf < 2; ++mf) {
        #pragma unroll
        for (int i = 0; i < 4; ++i) {
          const int row = mf * 16 + r0 + i;
          wsp[row * OUT_F + col0]      = acc[mf][0][i];
          wsp[row * OUT_F + col0 + 16] = acc[mf][1][i];
        }
      }
    } else {
      if (rep == 0) {     // atomics are not idempotent -> only rep 0
        #pragma unroll
        for (int mf = 0; mf < 2; ++mf) {
          #pragma unroll
          for (int i = 0; i < 4; ++i) {
            const int row = mf * 16 + r0 + i;
            atomicAdd(outp + row * OUT_F + col0,      acc[mf][0][i]);
            atomicAdd(outp + row * OUT_F + col0 + 16, acc[mf][1][i]);
          }
        }
      }
    }
  }
}

extern "C" void kernel_launch(void* const* d_in, const int* in_sizes, int n_in,
                              void* d_out, int out_size, void* d_ws, size_t ws_size,
                              hipStream_t stream) {
  const float* x    = (const float*)d_in[0];
  const int*   qwp  = (const int*)d_in[1];
  const int*   qzp  = (const int*)d_in[2];
  const float* scp  = (const float*)d_in[3];
  const float* bias = (const float*)d_in[4];
  float* out = (float*)d_out;

  const size_t ws_part = (size_t)KSPLIT * SLAB * sizeof(float);   // 22.5 MB
  const size_t xb_sz   = (size_t)MROWS * IN_F * 2;                // 256 KB

  if (ws_size >= ws_part + xb_sz) {
    float* ws = (float*)d_ws;
    _Float16* xb = (_Float16*)((char*)d_ws + ws_part);
    xconv<<<128, 256, 0, stream>>>(x, xb);
    awq_main<true, true><<<NBLK, 256, 0, stream>>>(x, xb, qwp, qzp, scp, ws);
    awq_reduce<<<SLAB / 4 / 256, 256, 0, stream>>>(ws, bias, out);
  } else {
    awq_init<<<dim3(43, 32), 256, 0, stream>>>(bias, out);
    awq_main<false, false><<<NBLK, 256, 0, stream>>>(x, nullptr, qwp, qzp, scp, out);
  }
}

// Round 12
// 41.370 us; speedup vs baseline: 1.8916x; 1.8916x over previous
//
#include <hip/hip_runtime.h>
#include <hip/hip_bf16.h>

// AWQ 4-bit linear: out[32,11008] = x[32,4096] @ ((q - z)*s) + bias
// Round 12: 1-WAVE BLOCKS for occupancy. Round-11 counters showed awq_main
// is latency-bound (Occ 31.5%, VALU 28%, Mfma 6%, HBM 3%): the per-tile
// q->dequant->ds_write->lgkm->ds_read->MFMA chain needs co-resident waves
// to hide, and 4-wave blocks gave only 2.5 waves/SIMD (ragged 1.34 dispatch
// rounds). Now: 5504 single-wave blocks (4KB LDS each) -> 21.5 waves/CU all
// resident in ONE round. Wave program identical to round 10 (verified
// swizzle + fp16 perm-dequant), w==0. KSPLIT=16, slab partials + reduce.

#define IN_F   4096
#define OUT_F  11008
#define WCOLS  1376
#define NCOLB  344                // 11008/32 col-blocks (32 cols per wave)
#define KSPLIT 16
#define CHUNK  (IN_F/KSPLIT)      // 256
#define NTILE  (CHUNK/32)         // 8
#define NBLK   (NCOLB*KSPLIT)     // 5504 = 8*688
#define MROWS  32
#define SLAB   (MROWS*OUT_F)      // floats per k-partial slab (352256)

typedef __attribute__((ext_vector_type(2))) _Float16 half2v;
typedef __attribute__((ext_vector_type(4))) _Float16 half4v;
typedef __attribute__((ext_vector_type(8))) _Float16 half8v;
typedef __attribute__((ext_vector_type(4))) float    f32x4;
typedef __attribute__((ext_vector_type(4))) int      int4v;

__device__ __forceinline__ f32x4 mfma16h(half8v a, half8v b, f32x4 c) {
  return __builtin_amdgcn_mfma_f32_16x16x32_f16(a, b, c, 0, 0, 0);
}
__device__ __forceinline__ half2v splat_h(float f) {
  unsigned short b = __builtin_bit_cast(unsigned short, (_Float16)f);
  unsigned int u = (unsigned int)b | ((unsigned int)b << 16);
  return __builtin_bit_cast(half2v, u);
}

__global__ void awq_init(const float* __restrict__ bias, float* __restrict__ out) {
  int o = blockIdx.x * 256 + threadIdx.x;
  out[blockIdx.y * OUT_F + o] = bias[o];
}

__global__ void xconv(const float* __restrict__ x, _Float16* __restrict__ xb) {
  int i = blockIdx.x * 256 + threadIdx.x;          // 128 blocks -> 32768 f32x4
  f32x4 v = ((const f32x4*)x)[i];
  half4v o;
  #pragma unroll
  for (int j = 0; j < 4; ++j) o[j] = (_Float16)v[j];
  ((half4v*)xb)[i] = o;
}

__global__ __launch_bounds__(256) void awq_reduce(
    const float* __restrict__ ws, const float* __restrict__ bias,
    float* __restrict__ out)
{
  const int i = blockIdx.x * 256 + threadIdx.x;    // f32x4 id, 88064 total
  const f32x4* w4 = (const f32x4*)ws;
  f32x4 s = w4[i];
  #pragma unroll
  for (int k = 1; k < KSPLIT; ++k) s += w4[k * (SLAB / 4) + i];
  const f32x4 b = *(const f32x4*)(bias + (i % (OUT_F / 4)) * 4);
  ((f32x4*)out)[i] = s + b;
}

template<bool PRE, bool TOWS>
__global__ __launch_bounds__(64, 6) void awq_main(
    const float* __restrict__ x, const _Float16* __restrict__ xb,
    const int* __restrict__ qw, const int* __restrict__ qz,
    const float* __restrict__ sc, float* __restrict__ outp)
{
  // Per-block (= per-wave) staging, swizzled: [buf][512 dwords] = 4 KB.
  __shared__ int lds[2][512];

  const int lane = threadIdx.x;        // blockDim = 64
  const int q4   = lane >> 4;          // MFMA k-octet
  const int cl   = lane & 15;          // MFMA col-in-frag
  const int ww   = lane & 3;           // dequant: word 0..3 -> cols 8ww..8ww+7
  const int kp2  = lane >> 2;          // dequant: k-pair 0..15
  const int qx   = kp2 >> 2;           // quad of kp
  const int kq   = kp2 & 3;            // kp within quad

  // Bijective XCD swizzle (5504 = 8*688)
  const int b  = blockIdx.x;
  const int L  = (b & 7) * (NBLK / 8) + (b >> 3);
  const int colb   = L % NCOLB;
  const int kchunk = L / NCOLB;

  const int cb  = colb * 32;           // first output column (32 per wave)
  const int wcb = colb * 4;            // first packed word
  const int K0  = kchunk * CHUNK;
  const int g0  = kchunk * (CHUNK / 128);   // 2 groups per chunk
  const int wq  = wcb + ww;            // lane's packed-word column

  // group constants: raw staging -> fp16 splat pairs
  f32x4 sra, srb; int zrw;
  half2v nz[8], ss[8];
  auto load_group_raw = [&](int g) {
    sra = *(const f32x4*)(sc + g * OUT_F + cb + ww * 8);
    srb = *(const f32x4*)(sc + g * OUT_F + cb + ww * 8 + 4);
    zrw = qz[g * WCOLS + wq];
  };
  auto conv_group = [&]() {
    #pragma unroll
    for (int l = 0; l < 8; ++l) {
      const int sh = 4 * (l >> 1) + 16 * (l & 1);   // 4*REV[l]
      const int zi = (zrw >> sh) & 15;
      nz[l] = splat_h(-(float)(1024 + zi));
      ss[l] = splat_h((l < 4) ? sra[l] : srb[l - 4]);
    }
  };
  auto load_q = [&](int t, int& q0, int& q1) {
    const int r = (K0 + t * 32 + 2 * kp2) * WCOLS + wq;
    q0 = qw[r];
    q1 = qw[r + WCOLS];
  };
  auto load_a = [&](int t, int mf) -> half8v {
    const int m = cl + 16 * mf;
    const int k = K0 + t * 32 + q4 * 8;
    if constexpr (PRE) {
      return *(const half8v*)(xb + m * IN_F + k);
    } else {
      const f32x4* xp = (const f32x4*)(x + m * IN_F + k);
      f32x4 lo = xp[0], hi = xp[1];
      half8v af;
      #pragma unroll
      for (int j = 0; j < 4; ++j) { af[j] = (_Float16)lo[j]; af[4+j] = (_Float16)hi[j]; }
      return af;
    }
  };
  // read B frag (cols cl / cl+16, k = 8q4..8q4+7), swizzle-inverse of store
  auto read_b = [&](int p, int frag) -> half8v {
    const int s0 = ((cl & 7) << 2) | (cl >> 3);
    const int qp = (q4 ^ ((cl >> 1) & 3)) << 2;
    const int idx = (s0 + 2 * frag) * 16 + qp;
    return __builtin_bit_cast(half8v, *(const int4v*)&lds[p][idx]);
  };

  // ---- prologue
  load_group_raw(g0);
  conv_group();
  int q0a, q1a, q0b, q1b, q0c, q1c;
  load_q(0, q0a, q1a);
  load_q(1, q0b, q1b);
  load_q(2, q0c, q1c);
  f32x4 acc[2][2] = {};

  #pragma unroll 4
  for (int t = 0; t < NTILE; ++t) {
    half8v a0 = load_a(t, 0), a1 = load_a(t, 1);
    int q0n = 0, q1n = 0;
    if (t + 3 < NTILE) load_q(t + 3, q0n, q1n);            // ring refill
    if (t == 2) load_group_raw(g0 + 1);                    // raw 2 tiles early
    if (t == 4) conv_group();                              // group 1 live t>=4

    // fp16 perm-dequant: gather (k0,k1) nibble-bytes per col, build exact
    // fp16 (1024+n), exact pk (q-z), pk mul by fp16 scale.
    const int p  = t & 1;
    const int h0 = (unsigned)q0a >> 4;
    const int h1 = (unsigned)q1a >> 4;
    #pragma unroll
    for (int l = 0; l < 8; ++l) {
      const int pb = 2 * (l & 1) + (l >> 2);               // source byte
      const unsigned sel = (unsigned)(4 + pb) | ((unsigned)(4 + pb) << 8)
                         | ((unsigned)pb << 16) | ((unsigned)pb << 24);
      const int x0 = ((l >> 1) & 1) ? h0 : q0a;
      const int x1 = ((l >> 1) & 1) ? h1 : q1a;
      unsigned P = __builtin_amdgcn_perm((unsigned)x0, (unsigned)x1, sel);
      unsigned W = (P & 0x000F000Fu) | 0x64006400u;        // h2: 1024+n
      half2v wh = (__builtin_bit_cast(half2v, W) + nz[l]) * ss[l];
      // store col c=8ww+l at slot l*4+ww, quad qx^((l>>1)&3), elem kq
      const int idx = (l * 4 + ww) * 16 + ((qx ^ ((l >> 1) & 3)) << 2) + kq;
      lds[p][idx] = __builtin_bit_cast(int, wh);
    }
    // no barrier: same-wave ds_write -> ds_read via lgkmcnt only

    half8v bf0 = read_b(p, 0);
    half8v bf1 = read_b(p, 1);

    acc[0][0] = mfma16h(a0, bf0, acc[0][0]);
    acc[0][1] = mfma16h(a0, bf1, acc[0][1]);
    acc[1][0] = mfma16h(a1, bf0, acc[1][0]);
    acc[1][1] = mfma16h(a1, bf1, acc[1][1]);

    q0a = q0b; q1a = q1b;
    q0b = q0c; q1b = q1c;
    q0c = q0n; q1c = q1n;
  }

  // ---- epilogue
  const int col0 = cb + cl;
  const int r0 = q4 * 4;
  if constexpr (TOWS) {
    float* wsp = outp + kchunk * SLAB;
    #pragma unroll
    for (int mf = 0; mf < 2; ++mf) {
      #pragma unroll
      for (int i = 0; i < 4; ++i) {
        const int row = mf * 16 + r0 + i;
        wsp[row * OUT_F + col0]      = acc[mf][0][i];
        wsp[row * OUT_F + col0 + 16] = acc[mf][1][i];
      }
    }
  } else {
    #pragma unroll
    for (int mf = 0; mf < 2; ++mf) {
      #pragma unroll
      for (int i = 0; i < 4; ++i) {
        const int row = mf * 16 + r0 + i;
        atomicAdd(outp + row * OUT_F + col0,      acc[mf][0][i]);
        atomicAdd(outp + row * OUT_F + col0 + 16, acc[mf][1][i]);
      }
    }
  }
}

extern "C" void kernel_launch(void* const* d_in, const int* in_sizes, int n_in,
                              void* d_out, int out_size, void* d_ws, size_t ws_size,
                              hipStream_t stream) {
  const float* x    = (const float*)d_in[0];
  const int*   qwp  = (const int*)d_in[1];
  const int*   qzp  = (const int*)d_in[2];
  const float* scp  = (const float*)d_in[3];
  const float* bias = (const float*)d_in[4];
  float* out = (float*)d_out;

  const size_t ws_part = (size_t)KSPLIT * SLAB * sizeof(float);   // 22.5 MB
  const size_t xb_sz   = (size_t)MROWS * IN_F * 2;                // 256 KB

  if (ws_size >= ws_part + xb_sz) {
    float* ws = (float*)d_ws;
    _Float16* xb = (_Float16*)((char*)d_ws + ws_part);
    xconv<<<128, 256, 0, stream>>>(x, xb);
    awq_main<true, true><<<NBLK, 64, 0, stream>>>(x, xb, qwp, qzp, scp, ws);
    awq_reduce<<<SLAB / 4 / 256, 256, 0, stream>>>(ws, bias, out);
  } else {
    awq_init<<<dim3(43, 32), 256, 0, stream>>>(bias, out);
    awq_main<false, false><<<NBLK, 64, 0, stream>>>(x, nullptr, qwp, qzp, scp, out);
  }
}

// Round 13
// 38.971 us; speedup vs baseline: 2.0080x; 1.0616x over previous
//
#include <hip/hip_runtime.h>
#include <hip/hip_bf16.h>

// AWQ 4-bit linear: out[32,11008] = x[32,4096] @ ((q - z)*s) + bias
// Round 13: SINGLE-VARIABLE A/B vs round 10 (35.7us): launch_bounds
// (256,4) -> (256,6). Round-11 counters: Occ 31.5% (2.52 waves/SIMD),
// latency-bound. KSPLIT=16 gives 5.375 four-wave blocks/CU of demand;
// the old bound capped residency at 4 blocks/CU -> ragged rounds.
// Cap 6 >= 5.375 -> ALL blocks co-resident in one dispatch round.
// (Round-12 lesson: 1-wave blocks throttle on workgroup dispatch rate —
// TLP must come from multi-wave blocks.) Wave program = round 10 verbatim.

#define IN_F   4096
#define OUT_F  11008
#define WCOLS  1376
#define NCOLB  86                 // 11008/128
#define KSPLIT 16
#define CHUNK  (IN_F/KSPLIT)      // 256
#define NTILE  (CHUNK/32)         // 8
#define NBLK   (NCOLB*KSPLIT)     // 1376
#define MROWS  32
#define SLAB   (MROWS*OUT_F)      // floats per k-partial slab (352256)

typedef __attribute__((ext_vector_type(2))) _Float16 half2v;
typedef __attribute__((ext_vector_type(4))) _Float16 half4v;
typedef __attribute__((ext_vector_type(8))) _Float16 half8v;
typedef __attribute__((ext_vector_type(4))) float    f32x4;
typedef __attribute__((ext_vector_type(4))) int      int4v;

__device__ __forceinline__ f32x4 mfma16h(half8v a, half8v b, f32x4 c) {
  return __builtin_amdgcn_mfma_f32_16x16x32_f16(a, b, c, 0, 0, 0);
}
__device__ __forceinline__ half2v splat_h(float f) {
  unsigned short b = __builtin_bit_cast(unsigned short, (_Float16)f);
  unsigned int u = (unsigned int)b | ((unsigned int)b << 16);
  return __builtin_bit_cast(half2v, u);
}

__global__ void awq_init(const float* __restrict__ bias, float* __restrict__ out) {
  int o = blockIdx.x * 256 + threadIdx.x;
  out[blockIdx.y * OUT_F + o] = bias[o];
}

__global__ void xconv(const float* __restrict__ x, _Float16* __restrict__ xb) {
  int i = blockIdx.x * 256 + threadIdx.x;          // 128 blocks -> 32768 f32x4
  f32x4 v = ((const f32x4*)x)[i];
  half4v o;
  #pragma unroll
  for (int j = 0; j < 4; ++j) o[j] = (_Float16)v[j];
  ((half4v*)xb)[i] = o;
}

__global__ __launch_bounds__(256) void awq_reduce(
    const float* __restrict__ ws, const float* __restrict__ bias,
    float* __restrict__ out)
{
  const int i = blockIdx.x * 256 + threadIdx.x;    // f32x4 id, 88064 total
  const f32x4* w4 = (const f32x4*)ws;
  f32x4 s = w4[i];
  #pragma unroll
  for (int k = 1; k < KSPLIT; ++k) s += w4[k * (SLAB / 4) + i];
  const f32x4 b = *(const f32x4*)(bias + (i % (OUT_F / 4)) * 4);
  ((f32x4*)out)[i] = s + b;
}

template<bool PRE, bool TOWS>
__global__ __launch_bounds__(256, 6) void awq_main(
    const float* __restrict__ x, const _Float16* __restrict__ xb,
    const int* __restrict__ qw, const int* __restrict__ qz,
    const float* __restrict__ sc, float* __restrict__ outp)
{
  // Per-wave private staging, swizzled: [buf][wave][512 dwords] = 16 KB.
  __shared__ int lds[2][4][512];

  const int tid  = threadIdx.x;
  const int w    = tid >> 6;           // wave -> 32-col subtile
  const int lane = tid & 63;
  const int q4   = lane >> 4;          // MFMA k-octet
  const int cl   = lane & 15;          // MFMA col-in-frag
  const int ww   = lane & 3;           // dequant: word 0..3 -> cols 8ww..8ww+7
  const int kp2  = lane >> 2;          // dequant: k-pair 0..15
  const int qx   = kp2 >> 2;           // quad of kp
  const int kq   = kp2 & 3;            // kp within quad

  // Bijective XCD swizzle (1376 = 8*172)
  const int b  = blockIdx.x;
  const int L  = (b & 7) * (NBLK / 8) + (b >> 3);
  const int colblk = L % NCOLB;
  const int kchunk = L / NCOLB;

  const int cb  = colblk * 128;        // first output column
  const int wcb = colblk * 16;         // first packed word
  const int K0  = kchunk * CHUNK;
  const int g0  = kchunk * (CHUNK / 128);   // 2 groups per chunk
  const int wq  = wcb + 4 * w + ww;    // lane's packed-word column

  // group constants: raw staging -> fp16 splat pairs
  f32x4 sra, srb; int zrw;
  half2v nz[8], ss[8];
  auto load_group_raw = [&](int g) {
    sra = *(const f32x4*)(sc + g * OUT_F + cb + w * 32 + ww * 8);
    srb = *(const f32x4*)(sc + g * OUT_F + cb + w * 32 + ww * 8 + 4);
    zrw = qz[g * WCOLS + wq];
  };
  auto conv_group = [&]() {
    #pragma unroll
    for (int l = 0; l < 8; ++l) {
      const int sh = 4 * (l >> 1) + 16 * (l & 1);   // 4*REV[l]
      const int zi = (zrw >> sh) & 15;
      nz[l] = splat_h(-(float)(1024 + zi));
      ss[l] = splat_h((l < 4) ? sra[l] : srb[l - 4]);
    }
  };
  auto load_q = [&](int t, int& q0, int& q1) {
    const int r = (K0 + t * 32 + 2 * kp2) * WCOLS + wq;
    q0 = qw[r];
    q1 = qw[r + WCOLS];
  };
  auto load_a = [&](int t, int mf) -> half8v {
    const int m = cl + 16 * mf;
    const int k = K0 + t * 32 + q4 * 8;
    if constexpr (PRE) {
      return *(const half8v*)(xb + m * IN_F + k);
    } else {
      const f32x4* xp = (const f32x4*)(x + m * IN_F + k);
      f32x4 lo = xp[0], hi = xp[1];
      half8v af;
      #pragma unroll
      for (int j = 0; j < 4; ++j) { af[j] = (_Float16)lo[j]; af[4+j] = (_Float16)hi[j]; }
      return af;
    }
  };
  // read B frag (cols cl / cl+16, k = 8q4..8q4+7), swizzle-inverse of store
  auto read_b = [&](int p, int frag) -> half8v {
    const int s0 = ((cl & 7) << 2) | (cl >> 3);
    const int qp = (q4 ^ ((cl >> 1) & 3)) << 2;
    const int idx = (s0 + 2 * frag) * 16 + qp;
    return __builtin_bit_cast(half8v, *(const int4v*)&lds[p][w][idx]);
  };

  // ---- prologue
  load_group_raw(g0);
  conv_group();
  int q0a, q1a, q0b, q1b, q0c, q1c;
  load_q(0, q0a, q1a);
  load_q(1, q0b, q1b);
  load_q(2, q0c, q1c);
  f32x4 acc[2][2] = {};

  #pragma unroll 4
  for (int t = 0; t < NTILE; ++t) {
    half8v a0 = load_a(t, 0), a1 = load_a(t, 1);
    int q0n = 0, q1n = 0;
    if (t + 3 < NTILE) load_q(t + 3, q0n, q1n);            // ring refill
    if (t == 2) load_group_raw(g0 + 1);                    // raw 2 tiles early
    if (t == 4) conv_group();                              // group 1 live t>=4

    // fp16 perm-dequant: gather (k0,k1) nibble-bytes per col, build exact
    // fp16 (1024+n), exact pk (q-z), pk mul by fp16 scale.
    const int p  = t & 1;
    const int h0 = (unsigned)q0a >> 4;
    const int h1 = (unsigned)q1a >> 4;
    #pragma unroll
    for (int l = 0; l < 8; ++l) {
      const int pb = 2 * (l & 1) + (l >> 2);               // source byte
      const unsigned sel = (unsigned)(4 + pb) | ((unsigned)(4 + pb) << 8)
                         | ((unsigned)pb << 16) | ((unsigned)pb << 24);
      const int x0 = ((l >> 1) & 1) ? h0 : q0a;
      const int x1 = ((l >> 1) & 1) ? h1 : q1a;
      unsigned P = __builtin_amdgcn_perm((unsigned)x0, (unsigned)x1, sel);
      unsigned W = (P & 0x000F000Fu) | 0x64006400u;        // h2: 1024+n
      half2v wh = (__builtin_bit_cast(half2v, W) + nz[l]) * ss[l];
      // store col c=ww*8+l at slot l*4+ww, quad qx^((l>>1)&3), elem kq
      const int idx = (l * 4 + ww) * 16 + ((qx ^ ((l >> 1) & 3)) << 2) + kq;
      lds[p][w][idx] = __builtin_bit_cast(int, wh);
    }
    // no barrier: same-wave ds_write -> ds_read via lgkmcnt only

    half8v bf0 = read_b(p, 0);
    half8v bf1 = read_b(p, 1);

    acc[0][0] = mfma16h(a0, bf0, acc[0][0]);
    acc[0][1] = mfma16h(a0, bf1, acc[0][1]);
    acc[1][0] = mfma16h(a1, bf0, acc[1][0]);
    acc[1][1] = mfma16h(a1, bf1, acc[1][1]);

    q0a = q0b; q1a = q1b;
    q0b = q0c; q1b = q1c;
    q0c = q0n; q1c = q1n;
  }

  // ---- epilogue
  const int col0 = cb + w * 32 + cl;
  const int r0 = q4 * 4;
  if constexpr (TOWS) {
    float* wsp = outp + kchunk * SLAB;
    #pragma unroll
    for (int mf = 0; mf < 2; ++mf) {
      #pragma unroll
      for (int i = 0; i < 4; ++i) {
        const int row = mf * 16 + r0 + i;
        wsp[row * OUT_F + col0]      = acc[mf][0][i];
        wsp[row * OUT_F + col0 + 16] = acc[mf][1][i];
      }
    }
  } else {
    #pragma unroll
    for (int mf = 0; mf < 2; ++mf) {
      #pragma unroll
      for (int i = 0; i < 4; ++i) {
        const int row = mf * 16 + r0 + i;
        atomicAdd(outp + row * OUT_F + col0,      acc[mf][0][i]);
        atomicAdd(outp + row * OUT_F + col0 + 16, acc[mf][1][i]);
      }
    }
  }
}

extern "C" void kernel_launch(void* const* d_in, const int* in_sizes, int n_in,
                              void* d_out, int out_size, void* d_ws, size_t ws_size,
                              hipStream_t stream) {
  const float* x    = (const float*)d_in[0];
  const int*   qwp  = (const int*)d_in[1];
  const int*   qzp  = (const int*)d_in[2];
  const float* scp  = (const float*)d_in[3];
  const float* bias = (const float*)d_in[4];
  float* out = (float*)d_out;

  const size_t ws_part = (size_t)KSPLIT * SLAB * sizeof(float);   // 22.5 MB
  const size_t xb_sz   = (size_t)MROWS * IN_F * 2;                // 256 KB

  if (ws_size >= ws_part + xb_sz) {
    float* ws = (float*)d_ws;
    _Float16* xb = (_Float16*)((char*)d_ws + ws_part);
    xconv<<<128, 256, 0, stream>>>(x, xb);
    awq_main<true, true><<<NBLK, 256, 0, stream>>>(x, xb, qwp, qzp, scp, ws);
    awq_reduce<<<SLAB / 4 / 256, 256, 0, stream>>>(ws, bias, out);
  } else {
    awq_init<<<dim3(43, 32), 256, 0, stream>>>(bias, out);
    awq_main<false, false><<<NBLK, 256, 0, stream>>>(x, nullptr, qwp, qzp, scp, out);
  }
}

// Round 14
// 33.910 us; speedup vs baseline: 2.3077x; 1.1493x over previous
//
#include <hip/hip_runtime.h>
#include <hip/hip_bf16.h>

// AWQ 4-bit linear: out[32,11008] = x[32,4096] @ ((q - z)*s) + bias
// Round 14: R6 base (best-known main = 16.9us: barriered block-wide LDS,
// bf16 fmaf dequant, KSPLIT=16, slab+reduce) + Q-HOIST: all 8 tiles' qweight
// loads issued in the PROLOGUE into registers (q[8][2], full unroll ->
// static indexing). Mechanism: per-tile __syncthreads emits vmcnt(0), which
// drained in-flight q prefetches (HBM, ~600-900cy) every tile; and in
// barrier-free variants vmcnt's in-order completion made fast a-loads queue
// behind slow q-loads (HOL). Hoisting moves the whole q drain to ONE
// prologue stall; in-loop VMEM is then L2-hot a-loads only (~200cy, hidden
// under dequant VALU).

#define IN_F   4096
#define OUT_F  11008
#define WCOLS  1376
#define NCOLB  86                 // 11008/128
#define KSPLIT 16
#define CHUNK  (IN_F/KSPLIT)      // 256
#define NTILE  (CHUNK/32)         // 8
#define NBLK   (NCOLB*KSPLIT)     // 1376
#define MROWS  32
#define SLAB   (MROWS*OUT_F)      // floats per k-partial slab (352256)

typedef __attribute__((ext_vector_type(8))) short  short8;
typedef __attribute__((ext_vector_type(4))) short  short4v;
typedef __attribute__((ext_vector_type(4))) float  f32x4;
typedef __attribute__((ext_vector_type(4))) int    int4v;

__device__ __forceinline__ short f2bf(float f) {
  return (short)__builtin_bit_cast(unsigned short, (__bf16)f);
}
__device__ __forceinline__ f32x4 mfma16(short8 a, short8 b, f32x4 c) {
  return __builtin_amdgcn_mfma_f32_16x16x32_bf16(a, b, c, 0, 0, 0);
}

__global__ void awq_init(const float* __restrict__ bias, float* __restrict__ out) {
  int o = blockIdx.x * 256 + threadIdx.x;
  out[blockIdx.y * OUT_F + o] = bias[o];
}

__global__ void xconv(const float* __restrict__ x, unsigned short* __restrict__ xb) {
  int i = blockIdx.x * 256 + threadIdx.x;          // 128 blocks -> 32768 f32x4
  f32x4 v = ((const f32x4*)x)[i];
  short4v o;
  #pragma unroll
  for (int j = 0; j < 4; ++j) o[j] = f2bf(v[j]);
  ((short4v*)xb)[i] = o;
}

__global__ __launch_bounds__(256) void awq_reduce(
    const float* __restrict__ ws, const float* __restrict__ bias,
    float* __restrict__ out)
{
  const int i = blockIdx.x * 256 + threadIdx.x;    // f32x4 id, 88064 total
  const f32x4* w4 = (const f32x4*)ws;
  f32x4 s = w4[i];
  #pragma unroll
  for (int k = 1; k < KSPLIT; ++k) s += w4[k * (SLAB / 4) + i];
  const f32x4 b = *(const f32x4*)(bias + (i % (OUT_F / 4)) * 4);
  ((f32x4*)out)[i] = s + b;
}

template<bool PRE, bool TOWS>
__global__ __launch_bounds__(256, 4) void awq_main(
    const float* __restrict__ x, const unsigned short* __restrict__ xb,
    const int* __restrict__ qw, const int* __restrict__ qz,
    const float* __restrict__ sc, float* __restrict__ outp)
{
  // [col 0..127][k-pair 0..15] dwords, double-buffered: 2 x 8KB.
  __shared__ int lds[2][2048];

  const int tid  = threadIdx.x;
  const int w    = tid >> 6;           // wave -> 32-col subtile
  const int lane = tid & 63;
  const int q4   = lane >> 4;

  // Bijective XCD swizzle (1376 = 8*172)
  const int b  = blockIdx.x;
  const int L  = (b & 7) * (NBLK / 8) + (b >> 3);
  const int colblk = L % NCOLB;
  const int kchunk = L / NCOLB;

  const int cb  = colblk * 128;        // first output column
  const int wcb = colblk * 16;         // first packed word
  const int K0  = kchunk * CHUNK;
  const int g0  = kchunk * (CHUNK / 128);   // 2 groups per chunk

  const int wr = tid & 15;             // word within block -> cols 8wr..8wr+7
  const int kp = tid >> 4;             // k-pair 0..15 -> k = 2kp, 2kp+1

  // group scale/zero: raw staging -> converted s8/zs8
  f32x4 sra, srb; int zrw;
  float s8[8], zs8[8];
  auto load_group_raw = [&](int g) {
    sra = *(const f32x4*)(sc + g * OUT_F + cb + 8 * wr);
    srb = *(const f32x4*)(sc + g * OUT_F + cb + 8 * wr + 4);
    zrw = qz[g * WCOLS + wcb + wr];
  };
  auto conv_group = [&]() {
    #pragma unroll
    for (int j = 0; j < 8; ++j) {
      const int sh = 4 * (j >> 1) + 16 * (j & 1);   // shift = 4*REV[j]
      const float sv = (j < 4) ? sra[j] : srb[j - 4];
      s8[j]  = sv;
      zs8[j] = -(float)((zrw >> sh) & 15) * sv;
    }
  };
  auto load_q = [&](int t, int& q0, int& q1) {
    const int r = (K0 + t * 32 + 2 * kp) * WCOLS + wcb + wr;
    q0 = qw[r];
    q1 = qw[r + WCOLS];
  };
  auto load_a = [&](int t, int mf) -> short8 {
    const int m = (lane & 15) + 16 * mf;
    const int k = K0 + t * 32 + q4 * 8;
    if constexpr (PRE) {
      return *(const short8*)(xb + m * IN_F + k);
    } else {
      const f32x4* xp = (const f32x4*)(x + m * IN_F + k);
      f32x4 lo = xp[0], hi = xp[1];
      short8 af;
      #pragma unroll
      for (int j = 0; j < 4; ++j) { af[j] = f2bf(lo[j]); af[4 + j] = f2bf(hi[j]); }
      return af;
    }
  };
  auto read_b = [&](int p, int c) -> short8 {
    const int idx = c * 16 + 4 * (q4 ^ ((c >> 3) & 3));   // 16B-aligned
    return __builtin_bit_cast(short8, *(const int4v*)&lds[p][idx]);
  };

  // ---- prologue: group-0 raw, then ALL q loads (one drain at t=0 barrier),
  // then group-0 convert (waits only the raws, q's keep flying).
  load_group_raw(g0);
  int qa[NTILE], qb[NTILE];
  #pragma unroll
  for (int t = 0; t < NTILE; ++t) load_q(t, qa[t], qb[t]);
  conv_group();
  f32x4 acc[2][2] = {};

  #pragma unroll
  for (int t = 0; t < NTILE; ++t) {
    // in-loop VMEM = a-loads only (L2-hot, hidden under dequant VALU)
    short8 a0 = load_a(t, 0), a1 = load_a(t, 1);
    if (t == 2) load_group_raw(g0 + 1);   // raw 2 tiles early (drained once)
    if (t == 4) conv_group();             // group 1 live for tiles 4..7

    // dequant 16 nibbles -> 8 packed bf16x2 -> LDS [col][k] (swizzled k-pair)
    const int p = t & 1;
    const int kps = kp ^ ((wr & 3) << 2);
    #pragma unroll
    for (int j = 0; j < 8; ++j) {
      const int sh = 4 * (j >> 1) + 16 * (j & 1);
      const float lo = fmaf((float)((qa[t] >> sh) & 15), s8[j], zs8[j]);
      const float hi = fmaf((float)((qb[t] >> sh) & 15), s8[j], zs8[j]);
      const unsigned int pk =
          (unsigned int)(unsigned short)__builtin_bit_cast(unsigned short, (__bf16)lo) |
          ((unsigned int)(unsigned short)__builtin_bit_cast(unsigned short, (__bf16)hi) << 16);
      lds[p][(8 * wr + j) * 16 + kps] = (int)pk;
    }
    __syncthreads();

    const int c0 = w * 32 + (lane & 15);
    short8 bf0 = read_b(p, c0);
    short8 bf1 = read_b(p, c0 + 16);

    acc[0][0] = mfma16(a0, bf0, acc[0][0]);
    acc[0][1] = mfma16(a0, bf1, acc[0][1]);
    acc[1][0] = mfma16(a1, bf0, acc[1][0]);
    acc[1][1] = mfma16(a1, bf1, acc[1][1]);
  }

  // ---- epilogue
  const int col0 = cb + w * 32 + (lane & 15);
  const int r0 = q4 * 4;
  if constexpr (TOWS) {
    // plain stores to this k-chunk's private partial slab
    float* wsp = outp + kchunk * SLAB;
    #pragma unroll
    for (int mf = 0; mf < 2; ++mf) {
      #pragma unroll
      for (int i = 0; i < 4; ++i) {
        const int row = mf * 16 + r0 + i;
        wsp[row * OUT_F + col0]      = acc[mf][0][i];
        wsp[row * OUT_F + col0 + 16] = acc[mf][1][i];
      }
    }
  } else {
    // fallback: fp32 atomics onto bias-initialized out
    #pragma unroll
    for (int mf = 0; mf < 2; ++mf) {
      #pragma unroll
      for (int i = 0; i < 4; ++i) {
        const int row = mf * 16 + r0 + i;
        atomicAdd(outp + row * OUT_F + col0,      acc[mf][0][i]);
        atomicAdd(outp + row * OUT_F + col0 + 16, acc[mf][1][i]);
      }
    }
  }
}

extern "C" void kernel_launch(void* const* d_in, const int* in_sizes, int n_in,
                              void* d_out, int out_size, void* d_ws, size_t ws_size,
                              hipStream_t stream) {
  const float* x    = (const float*)d_in[0];
  const int*   qwp  = (const int*)d_in[1];
  const int*   qzp  = (const int*)d_in[2];
  const float* scp  = (const float*)d_in[3];
  const float* bias = (const float*)d_in[4];
  float* out = (float*)d_out;

  const size_t ws_part = (size_t)KSPLIT * SLAB * sizeof(float);   // 22.5 MB
  const size_t xb_sz   = (size_t)MROWS * IN_F * 2;                // 256 KB

  if (ws_size >= ws_part + xb_sz) {
    float* ws = (float*)d_ws;
    unsigned short* xb = (unsigned short*)((char*)d_ws + ws_part);
    xconv<<<128, 256, 0, stream>>>(x, xb);
    awq_main<true, true><<<NBLK, 256, 0, stream>>>(x, xb, qwp, qzp, scp, ws);
    awq_reduce<<<SLAB / 4 / 256, 256, 0, stream>>>(ws, bias, out);
  } else {
    awq_init<<<dim3(43, 32), 256, 0, stream>>>(bias, out);
    awq_main<false, false><<<NBLK, 256, 0, stream>>>(x, nullptr, qwp, qzp, scp, out);
  }
}

// Round 15
// 33.595 us; speedup vs baseline: 2.3294x; 1.0094x over previous
//
#include <hip/hip_runtime.h>
#include <hip/hip_bf16.h>

// AWQ 4-bit linear: out[32,11008] = x[32,4096] @ ((q - z)*s) + bias
// Round 15: consolidation of the 14-round ledger.
//  - main: R9's verified bf16 wave program (per-wave private LDS, [col][kp]
//    XOR swizzle, fmaf dequant) re-binned into 512-THREAD BARRIER-FREE
//    blocks: 688 blocks x 8 waves, demand 2.69 blocks/CU < cap 3
//    (launch_bounds(512,6)) -> ALL 21.5 waves/CU co-resident, no ragged
//    dispatch rounds (R10's 5.375 vs cap 4), no barrier convoys, no
//    1-wave dispatch throttle (R12). Full q-hoist (8 tiles -> regs) so
//    the loop has no long-latency VMEM dependency.
//  - reduce: bf16 partial slabs (11.25 MB vs 22.5) -> ~halves reduce time.

#define IN_F   4096
#define OUT_F  11008
#define WCOLS  1376
#define NCOLB  43                 // 256-col blocks
#define KSPLIT 16
#define CHUNK  (IN_F/KSPLIT)      // 256
#define NTILE  (CHUNK/32)         // 8
#define NBLK   (NCOLB*KSPLIT)     // 688 = 8*86
#define MROWS  32
#define SLAB   (MROWS*OUT_F)      // elements per k-partial slab (352256)

typedef __attribute__((ext_vector_type(8))) short  short8;
typedef __attribute__((ext_vector_type(4))) short  short4v;
typedef __attribute__((ext_vector_type(4))) unsigned short ushort4v;
typedef __attribute__((ext_vector_type(4))) float  f32x4;
typedef __attribute__((ext_vector_type(4))) int    int4v;

__device__ __forceinline__ short f2bf(float f) {
  return (short)__builtin_bit_cast(unsigned short, (__bf16)f);
}
__device__ __forceinline__ unsigned short f2bfu(float f) {
  return __builtin_bit_cast(unsigned short, (__bf16)f);
}
__device__ __forceinline__ float bf2f(unsigned short u) {
  return __builtin_bit_cast(float, ((unsigned int)u) << 16);
}
__device__ __forceinline__ f32x4 mfma16(short8 a, short8 b, f32x4 c) {
  return __builtin_amdgcn_mfma_f32_16x16x32_bf16(a, b, c, 0, 0, 0);
}

__global__ void awq_init(const float* __restrict__ bias, float* __restrict__ out) {
  int o = blockIdx.x * 256 + threadIdx.x;
  out[blockIdx.y * OUT_F + o] = bias[o];
}

__global__ void xconv(const float* __restrict__ x, unsigned short* __restrict__ xb) {
  int i = blockIdx.x * 256 + threadIdx.x;          // 128 blocks -> 32768 f32x4
  f32x4 v = ((const f32x4*)x)[i];
  short4v o;
  #pragma unroll
  for (int j = 0; j < 4; ++j) o[j] = f2bf(v[j]);
  ((short4v*)xb)[i] = o;
}

__global__ __launch_bounds__(256) void awq_reduce(
    const unsigned short* __restrict__ ws, const float* __restrict__ bias,
    float* __restrict__ out)
{
  const int i = blockIdx.x * 256 + threadIdx.x;    // 4-col id, 88064 total
  f32x4 s = *(const f32x4*)(bias + (i % (OUT_F / 4)) * 4);
  const ushort4v* w4 = (const ushort4v*)ws;
  #pragma unroll
  for (int k = 0; k < KSPLIT; ++k) {
    ushort4v v = w4[k * (SLAB / 4) + i];
    #pragma unroll
    for (int j = 0; j < 4; ++j) s[j] += bf2f(v[j]);
  }
  ((f32x4*)out)[i] = s;
}

template<bool PRE, bool TOWS>
__global__ __launch_bounds__(512, 6) void awq_main(
    const float* __restrict__ x, const unsigned short* __restrict__ xb,
    const int* __restrict__ qw, const int* __restrict__ qz,
    const float* __restrict__ sc, void* __restrict__ outp)
{
  // Per-wave private staging: [buf][wave][32 col][16 kp] dwords = 32 KB.
  __shared__ int lds[2][8][512];

  const int tid  = threadIdx.x;
  const int w    = tid >> 6;           // wave 0..7 -> 32-col subtile
  const int lane = tid & 63;
  const int q4   = lane >> 4;          // MFMA k-octet
  const int cl   = lane & 15;          // MFMA col-in-frag
  const int ww   = lane & 3;           // dequant: word -> cols 8ww..8ww+7
  const int kp2  = lane >> 2;          // dequant: k-pair 0..15

  // Bijective XCD swizzle (688 = 8*86)
  const int b  = blockIdx.x;
  const int L  = (b & 7) * (NBLK / 8) + (b >> 3);
  const int colb   = L % NCOLB;
  const int kchunk = L / NCOLB;

  const int cb  = colb * 256;          // first output column of block
  const int wcb = colb * 32;           // first packed word of block
  const int K0  = kchunk * CHUNK;
  const int g0  = kchunk * (CHUNK / 128);   // 2 groups per chunk
  const int wq  = wcb + 4 * w + ww;    // lane's packed-word column

  // group scale/zero: raw staging -> converted s8/zs8
  f32x4 sra, srb; int zrw;
  float s8[8], zs8[8];
  auto load_group_raw = [&](int g) {
    sra = *(const f32x4*)(sc + g * OUT_F + cb + w * 32 + ww * 8);
    srb = *(const f32x4*)(sc + g * OUT_F + cb + w * 32 + ww * 8 + 4);
    zrw = qz[g * WCOLS + wq];
  };
  auto conv_group = [&]() {
    #pragma unroll
    for (int j = 0; j < 8; ++j) {
      const int sh = 4 * (j >> 1) + 16 * (j & 1);   // shift = 4*REV[j]
      const float sv = (j < 4) ? sra[j] : srb[j - 4];
      s8[j]  = sv;
      zs8[j] = -(float)((zrw >> sh) & 15) * sv;
    }
  };
  auto load_a = [&](int t, int mf) -> short8 {
    const int m = cl + 16 * mf;
    const int k = K0 + t * 32 + q4 * 8;
    if constexpr (PRE) {
      return *(const short8*)(xb + m * IN_F + k);
    } else {
      const f32x4* xp = (const f32x4*)(x + m * IN_F + k);
      f32x4 lo = xp[0], hi = xp[1];
      short8 af;
      #pragma unroll
      for (int j = 0; j < 4; ++j) { af[j] = f2bf(lo[j]); af[4 + j] = f2bf(hi[j]); }
      return af;
    }
  };
  // read element (col c, kp=4q4+i): stored at c*16 + (kp ^ ((c>>3)<<2))
  // -> b128 at c*16 + 4*(q4 ^ ((c>>3)&3)) yields k-contiguous 8q4..8q4+7.
  auto read_b = [&](int p, int c) -> short8 {
    const int idx = c * 16 + 4 * (q4 ^ ((c >> 3) & 3));
    return __builtin_bit_cast(short8, *(const int4v*)&lds[p][w][idx]);
  };

  // ---- prologue: group-0 raw, ALL 8 tiles' q-loads into registers, convert.
  load_group_raw(g0);
  int qa[NTILE], qb[NTILE];
  #pragma unroll
  for (int t = 0; t < NTILE; ++t) {
    const int r = (K0 + t * 32 + 2 * kp2) * WCOLS + wq;
    qa[t] = qw[r];
    qb[t] = qw[r + WCOLS];
  }
  conv_group();
  f32x4 acc[2][2] = {};

  #pragma unroll
  for (int t = 0; t < NTILE; ++t) {
    // only in-loop VMEM: L2-hot a-loads (issued before group raw at t==2,
    // so vmcnt wait for a never waits the raw).
    short8 a0 = load_a(t, 0), a1 = load_a(t, 1);
    if (t == 2) load_group_raw(g0 + 1);   // 2 tiles early
    if (t == 4) conv_group();             // group 1 live for tiles 4..7

    // dequant 16 nibbles -> 8 packed bf16x2 -> private LDS (swizzled kp)
    const int p = t & 1;
    const int kps = kp2 ^ (ww << 2);
    #pragma unroll
    for (int j = 0; j < 8; ++j) {
      const int sh = 4 * (j >> 1) + 16 * (j & 1);
      const float lo = fmaf((float)((qa[t] >> sh) & 15), s8[j], zs8[j]);
      const float hi = fmaf((float)((qb[t] >> sh) & 15), s8[j], zs8[j]);
      const unsigned int pk =
          (unsigned int)(unsigned short)f2bf(lo) |
          ((unsigned int)(unsigned short)f2bf(hi) << 16);
      lds[p][w][(ww * 8 + j) * 16 + kps] = (int)pk;
    }
    // no barrier: same-wave ds_write -> ds_read ordering via lgkmcnt only

    short8 bf0 = read_b(p, cl);
    short8 bf1 = read_b(p, cl + 16);

    acc[0][0] = mfma16(a0, bf0, acc[0][0]);
    acc[0][1] = mfma16(a0, bf1, acc[0][1]);
    acc[1][0] = mfma16(a1, bf0, acc[1][0]);
    acc[1][1] = mfma16(a1, bf1, acc[1][1]);
  }

  // ---- epilogue
  const int col0 = cb + w * 32 + cl;
  const int r0 = q4 * 4;
  if constexpr (TOWS) {
    // bf16 partials to this k-chunk's private slab (plain stores)
    unsigned short* wsp = (unsigned short*)outp + kchunk * SLAB;
    #pragma unroll
    for (int mf = 0; mf < 2; ++mf) {
      #pragma unroll
      for (int i = 0; i < 4; ++i) {
        const int row = mf * 16 + r0 + i;
        wsp[row * OUT_F + col0]      = f2bfu(acc[mf][0][i]);
        wsp[row * OUT_F + col0 + 16] = f2bfu(acc[mf][1][i]);
      }
    }
  } else {
    // fallback: fp32 atomics onto bias-initialized out
    float* op = (float*)outp;
    #pragma unroll
    for (int mf = 0; mf < 2; ++mf) {
      #pragma unroll
      for (int i = 0; i < 4; ++i) {
        const int row = mf * 16 + r0 + i;
        atomicAdd(op + row * OUT_F + col0,      acc[mf][0][i]);
        atomicAdd(op + row * OUT_F + col0 + 16, acc[mf][1][i]);
      }
    }
  }
}

extern "C" void kernel_launch(void* const* d_in, const int* in_sizes, int n_in,
                              void* d_out, int out_size, void* d_ws, size_t ws_size,
                              hipStream_t stream) {
  const float* x    = (const float*)d_in[0];
  const int*   qwp  = (const int*)d_in[1];
  const int*   qzp  = (const int*)d_in[2];
  const float* scp  = (const float*)d_in[3];
  const float* bias = (const float*)d_in[4];
  float* out = (float*)d_out;

  const size_t ws_part = (size_t)KSPLIT * SLAB * 2;   // 11.25 MB (bf16)
  const size_t xb_sz   = (size_t)MROWS * IN_F * 2;    // 256 KB

  if (ws_size >= ws_part + xb_sz) {
    unsigned short* ws = (unsigned short*)d_ws;
    unsigned short* xb = (unsigned short*)((char*)d_ws + ws_part);
    xconv<<<128, 256, 0, stream>>>(x, xb);
    awq_main<true, true><<<NBLK, 512, 0, stream>>>(x, xb, qwp, qzp, scp, ws);
    awq_reduce<<<SLAB / 4 / 256, 256, 0, stream>>>(ws, bias, out);
  } else {
    awq_init<<<dim3(43, 32), 256, 0, stream>>>(bias, out);
    awq_main<false, false><<<NBLK, 512, 0, stream>>>(x, nullptr, qwp, qzp, scp, out);
  }
}

// Round 16
// 29.334 us; speedup vs baseline: 2.6677x; 1.1452x over previous
//
#include <hip/hip_runtime.h>
#include <hip/hip_bf16.h>

// AWQ 4-bit linear: out[32,11008] = x[32,4096] @ ((q - z)*s) + bias
// Round 16: ILP round — FEWER, FATTER WAVES. Ledger model: main is
// per-wave chain-latency bound (R12: 1-blk/CU -> 6.8us/block serial;
// R6/R11: 17us at 2.5 waves/SIMD); TLP knobs only moved residency, never
// waves-to-run. Now each wave owns 64 COLUMNS (two independent
// dequant->LDS->MFMA streams, h=0/1, sharing A-frags and k-range):
// waves 5504 -> 2752, per-wave latency ~flat (streams interleave in the
// 71% idle issue slots) -> wall ~halves. 688 blocks x 4 waves,
// 2.69 blocks/CU < cap 3 (launch_bounds(256,3)) -> one clean round.
// Verified R9/R15 formulas + h-offsets; q-hoist (32 dwords, static);
// bf16 slabs + reduce (R15).

#define IN_F   4096
#define OUT_F  11008
#define WCOLS  1376
#define NCOLB  43                 // 256-col blocks
#define KSPLIT 16
#define CHUNK  (IN_F/KSPLIT)      // 256
#define NTILE  (CHUNK/32)         // 8
#define NBLK   (NCOLB*KSPLIT)     // 688 = 8*86
#define MROWS  32
#define SLAB   (MROWS*OUT_F)      // elements per k-partial slab (352256)

typedef __attribute__((ext_vector_type(8))) short  short8;
typedef __attribute__((ext_vector_type(4))) short  short4v;
typedef __attribute__((ext_vector_type(4))) unsigned short ushort4v;
typedef __attribute__((ext_vector_type(4))) float  f32x4;
typedef __attribute__((ext_vector_type(4))) int    int4v;

__device__ __forceinline__ short f2bf(float f) {
  return (short)__builtin_bit_cast(unsigned short, (__bf16)f);
}
__device__ __forceinline__ unsigned short f2bfu(float f) {
  return __builtin_bit_cast(unsigned short, (__bf16)f);
}
__device__ __forceinline__ float bf2f(unsigned short u) {
  return __builtin_bit_cast(float, ((unsigned int)u) << 16);
}
__device__ __forceinline__ f32x4 mfma16(short8 a, short8 b, f32x4 c) {
  return __builtin_amdgcn_mfma_f32_16x16x32_bf16(a, b, c, 0, 0, 0);
}

__global__ void awq_init(const float* __restrict__ bias, float* __restrict__ out) {
  int o = blockIdx.x * 256 + threadIdx.x;
  out[blockIdx.y * OUT_F + o] = bias[o];
}

__global__ void xconv(const float* __restrict__ x, unsigned short* __restrict__ xb) {
  int i = blockIdx.x * 256 + threadIdx.x;          // 128 blocks -> 32768 f32x4
  f32x4 v = ((const f32x4*)x)[i];
  short4v o;
  #pragma unroll
  for (int j = 0; j < 4; ++j) o[j] = f2bf(v[j]);
  ((short4v*)xb)[i] = o;
}

__global__ __launch_bounds__(256) void awq_reduce(
    const unsigned short* __restrict__ ws, const float* __restrict__ bias,
    float* __restrict__ out)
{
  const int i = blockIdx.x * 256 + threadIdx.x;    // 4-col id, 88064 total
  f32x4 s = *(const f32x4*)(bias + (i % (OUT_F / 4)) * 4);
  const ushort4v* w4 = (const ushort4v*)ws;
  #pragma unroll
  for (int k = 0; k < KSPLIT; ++k) {
    ushort4v v = w4[k * (SLAB / 4) + i];
    #pragma unroll
    for (int j = 0; j < 4; ++j) s[j] += bf2f(v[j]);
  }
  ((f32x4*)out)[i] = s;
}

template<bool PRE, bool TOWS>
__global__ __launch_bounds__(256, 3) void awq_main(
    const float* __restrict__ x, const unsigned short* __restrict__ xb,
    const int* __restrict__ qw, const int* __restrict__ qz,
    const float* __restrict__ sc, void* __restrict__ outp)
{
  // Per-wave, per-half private staging: [buf][wave][half][512 dw] = 32 KB.
  __shared__ int lds[2][4][2][512];

  const int tid  = threadIdx.x;
  const int w    = tid >> 6;           // wave 0..3 -> 64-col stripe
  const int lane = tid & 63;
  const int q4   = lane >> 4;          // MFMA k-octet
  const int cl   = lane & 15;          // MFMA col-in-frag
  const int ww   = lane & 3;           // dequant: word -> cols 8ww..8ww+7
  const int kp2  = lane >> 2;          // dequant: k-pair 0..15
  const int kps  = kp2 ^ (ww << 2);    // swizzled k-pair slot (verified R9)

  // Bijective XCD swizzle (688 = 8*86)
  const int b  = blockIdx.x;
  const int L  = (b & 7) * (NBLK / 8) + (b >> 3);
  const int colb   = L % NCOLB;
  const int kchunk = L / NCOLB;

  const int cb  = colb * 256;          // first output column of block
  const int wcb = colb * 32;           // first packed word of block
  const int K0  = kchunk * CHUNK;
  const int g0  = kchunk * (CHUNK / 128);   // 2 groups per chunk
  const int cw  = cb + w * 64;         // wave's first column
  const int wqw = wcb + w * 8;         // wave's first packed word

  // group scale/zero per half: raw staging -> converted s8/zs8
  f32x4 sra[2], srb[2]; int zrw[2];
  float s8[2][8], zs8[2][8];
  auto load_group_raw = [&](int g) {
    #pragma unroll
    for (int h = 0; h < 2; ++h) {
      sra[h] = *(const f32x4*)(sc + g * OUT_F + cw + h * 32 + ww * 8);
      srb[h] = *(const f32x4*)(sc + g * OUT_F + cw + h * 32 + ww * 8 + 4);
      zrw[h] = qz[g * WCOLS + wqw + h * 4 + ww];
    }
  };
  auto conv_group = [&]() {
    #pragma unroll
    for (int h = 0; h < 2; ++h) {
      #pragma unroll
      for (int j = 0; j < 8; ++j) {
        const int sh = 4 * (j >> 1) + 16 * (j & 1);   // shift = 4*REV[j]
        const float sv = (j < 4) ? sra[h][j] : srb[h][j - 4];
        s8[h][j]  = sv;
        zs8[h][j] = -(float)((zrw[h] >> sh) & 15) * sv;
      }
    }
  };
  auto load_a = [&](int t, int mf) -> short8 {
    const int m = cl + 16 * mf;
    const int k = K0 + t * 32 + q4 * 8;
    if constexpr (PRE) {
      return *(const short8*)(xb + m * IN_F + k);
    } else {
      const f32x4* xp = (const f32x4*)(x + m * IN_F + k);
      f32x4 lo = xp[0], hi = xp[1];
      short8 af;
      #pragma unroll
      for (int j = 0; j < 4; ++j) { af[j] = f2bf(lo[j]); af[4 + j] = f2bf(hi[j]); }
      return af;
    }
  };
  // read (col c, kp=4q4+i) stored at c*16 + (kp ^ ((c>>3)<<2)):
  // b128 at c*16 + 4*(q4 ^ ((c>>3)&3)) -> k-contiguous 8q4..8q4+7.
  auto read_b = [&](int p, int h, int c) -> short8 {
    const int idx = c * 16 + 4 * (q4 ^ ((c >> 3) & 3));
    return __builtin_bit_cast(short8, *(const int4v*)&lds[p][w][h][idx]);
  };

  // ---- prologue: group-0 raws, ALL q-loads (8 tiles x 2 halves) to regs.
  load_group_raw(g0);
  int qa[NTILE][2], qb[NTILE][2];
  #pragma unroll
  for (int t = 0; t < NTILE; ++t) {
    #pragma unroll
    for (int h = 0; h < 2; ++h) {
      const int r = (K0 + t * 32 + 2 * kp2) * WCOLS + wqw + h * 4 + ww;
      qa[t][h] = qw[r];
      qb[t][h] = qw[r + WCOLS];
    }
  }
  conv_group();
  f32x4 acc[2][2][2] = {};   // [mf][h][cfrag]

  #pragma unroll
  for (int t = 0; t < NTILE; ++t) {
    // only in-loop VMEM: L2-hot a-loads, shared by both halves
    short8 a0 = load_a(t, 0), a1 = load_a(t, 1);
    if (t == 2) load_group_raw(g0 + 1);   // 2 tiles early, drained once
    if (t == 4) conv_group();             // group 1 live for tiles 4..7

    const int p = t & 1;
    // two independent dequant->LDS streams (h=0,1)
    #pragma unroll
    for (int h = 0; h < 2; ++h) {
      #pragma unroll
      for (int j = 0; j < 8; ++j) {
        const int sh = 4 * (j >> 1) + 16 * (j & 1);
        const float lo = fmaf((float)((qa[t][h] >> sh) & 15), s8[h][j], zs8[h][j]);
        const float hi = fmaf((float)((qb[t][h] >> sh) & 15), s8[h][j], zs8[h][j]);
        const unsigned int pk =
            (unsigned int)(unsigned short)f2bf(lo) |
            ((unsigned int)(unsigned short)f2bf(hi) << 16);
        lds[p][w][h][(ww * 8 + j) * 16 + kps] = (int)pk;
      }
    }
    // no barrier: same-wave ds_write -> ds_read via lgkmcnt only

    #pragma unroll
    for (int h = 0; h < 2; ++h) {
      short8 bf0 = read_b(p, h, cl);
      short8 bf1 = read_b(p, h, cl + 16);
      acc[0][h][0] = mfma16(a0, bf0, acc[0][h][0]);
      acc[0][h][1] = mfma16(a0, bf1, acc[0][h][1]);
      acc[1][h][0] = mfma16(a1, bf0, acc[1][h][0]);
      acc[1][h][1] = mfma16(a1, bf1, acc[1][h][1]);
    }
  }

  // ---- epilogue
  const int r0 = q4 * 4;
  if constexpr (TOWS) {
    unsigned short* wsp = (unsigned short*)outp + kchunk * SLAB;
    #pragma unroll
    for (int mf = 0; mf < 2; ++mf) {
      #pragma unroll
      for (int h = 0; h < 2; ++h) {
        #pragma unroll
        for (int i = 0; i < 4; ++i) {
          const int row = mf * 16 + r0 + i;
          const int c0  = cw + h * 32 + cl;
          wsp[row * OUT_F + c0]      = f2bfu(acc[mf][h][0][i]);
          wsp[row * OUT_F + c0 + 16] = f2bfu(acc[mf][h][1][i]);
        }
      }
    }
  } else {
    float* op = (float*)outp;
    #pragma unroll
    for (int mf = 0; mf < 2; ++mf) {
      #pragma unroll
      for (int h = 0; h < 2; ++h) {
        #pragma unroll
        for (int i = 0; i < 4; ++i) {
          const int row = mf * 16 + r0 + i;
          const int c0  = cw + h * 32 + cl;
          atomicAdd(op + row * OUT_F + c0,      acc[mf][h][0][i]);
          atomicAdd(op + row * OUT_F + c0 + 16, acc[mf][h][1][i]);
        }
      }
    }
  }
}

extern "C" void kernel_launch(void* const* d_in, const int* in_sizes, int n_in,
                              void* d_out, int out_size, void* d_ws, size_t ws_size,
                              hipStream_t stream) {
  const float* x    = (const float*)d_in[0];
  const int*   qwp  = (const int*)d_in[1];
  const int*   qzp  = (const int*)d_in[2];
  const float* scp  = (const float*)d_in[3];
  const float* bias = (const float*)d_in[4];
  float* out = (float*)d_out;

  const size_t ws_part = (size_t)KSPLIT * SLAB * 2;   // 11.25 MB (bf16)
  const size_t xb_sz   = (size_t)MROWS * IN_F * 2;    // 256 KB

  if (ws_size >= ws_part + xb_sz) {
    unsigned short* ws = (unsigned short*)d_ws;
    unsigned short* xb = (unsigned short*)((char*)d_ws + ws_part);
    xconv<<<128, 256, 0, stream>>>(x, xb);
    awq_main<true, true><<<NBLK, 256, 0, stream>>>(x, xb, qwp, qzp, scp, ws);
    awq_reduce<<<SLAB / 4 / 256, 256, 0, stream>>>(ws, bias, out);
  } else {
    awq_init<<<dim3(43, 32), 256, 0, stream>>>(bias, out);
    awq_main<false, false><<<NBLK, 256, 0, stream>>>(x, nullptr, qwp, qzp, scp, out);
  }
}